// Round 1
// 41.358 us; speedup vs baseline: 1.6006x; 1.6006x over previous
//
#include <hip/hip_runtime.h>
#include <hip/hip_bf16.h>

// LearnableChebyshevKernelAttention, MI355X — MFMA, barrier-free main loop.
// B=2, Q=M=1024, DIM=3, H=8, V=64, OUT=512, C=8.
//
// prep:      values [b,m,h,v] f32 -> Vt [b,h,v,m] bf16, out_w f32 -> bf16.
// cheb_attn: grid (32,8,2) = (qt of 32 q, h, b), block 512 (8 waves).
//            wave w: wg=w&1 (16-q band), g=w>>2? no: g=w>>1 (m quarter, 256 m).
//            Scores are computed DIRECTLY in the MFMA A-fragment register
//            layout (lane arow=lane&15 owns q=band+arow; koct=lane>>4 owns
//            m = m0 + kk*32 + koct*8 + j) -> no score LDS round-trip and no
//            per-tile barriers. kp staged SoA in LDS, read as b128.
//            4-way m-split partials + L1 combined once in the epilogue.
//            flat written as bf16 (proj rounded it to bf16 anyway).
// proj:      flat bf16 [2048,512] @ Wb[n,k]^T via MFMA, frags straight from
//            L2-resident global, no LDS, no barriers. grid (32,16), block 256.

typedef __attribute__((ext_vector_type(8))) short short8v;
typedef __attribute__((ext_vector_type(4))) short short4v;
typedef __attribute__((ext_vector_type(4))) float f32x4;

#define EPSF 1e-5f

__device__ __forceinline__ float frcp(float x) { return __builtin_amdgcn_rcpf(x); }
__device__ __forceinline__ short f2bf(float f) {
    __hip_bfloat16 h = __float2bfloat16(f);   // RNE
    return *reinterpret_cast<short*>(&h);
}

// ws layout (shorts): Vt bf16 [2*8*64*1024] | Wb bf16 [512*512] | flat bf16 [2*1024*512]
#define VT_ELEMS   (2u * 8u * 64u * 1024u)
#define WB_OFF_S   (VT_ELEMS)
#define FLAT_OFF_S (VT_ELEMS + 512u * 512u)

// ---------------------------------------------------------------- prep
// grid 288: blocks 0..255 transpose one (b,h,64m) values tile; 256..287 convert W.
__global__ __launch_bounds__(256) void prep(
    const float* __restrict__ vals, const float* __restrict__ outw,
    short* __restrict__ vt, short* __restrict__ wb)
{
    const int bid = blockIdx.x, t = threadIdx.x;
    if (bid < 256) {
        __shared__ float sf[64 * 68];
        const int b = bid >> 7, h = (bid >> 4) & 7, m0 = (bid & 15) * 64;
        #pragma unroll
        for (int fi = 0; fi < 4; ++fi) {
            const int idx = fi * 256 + t, mr = idx >> 4, c4 = idx & 15;
            const float4 v4 = *(const float4*)&vals[
                (((size_t)b * 1024 + m0 + mr) * 8 + h) * 64 + c4 * 4];
            *(float4*)&sf[mr * 68 + c4 * 4] = v4;
        }
        __syncthreads();
        const int v = t >> 2, mo = t & 3;
        short8v o0, o1;
        #pragma unroll
        for (int i = 0; i < 8; ++i) o0[i] = f2bf(sf[(mo * 16 + i) * 68 + v]);
        #pragma unroll
        for (int i = 0; i < 8; ++i) o1[i] = f2bf(sf[(mo * 16 + 8 + i) * 68 + v]);
        const size_t ob = ((size_t)(b * 8 + h) * 64 + v) * 1024 + m0 + mo * 16;
        *(short8v*)&vt[ob] = o0;
        *(short8v*)&vt[ob + 8] = o1;
    } else {
        const int wi = bid - 256;            // 0..31, 8192 floats each
        #pragma unroll
        for (int k = 0; k < 8; ++k) {
            const int fidx = wi * 8192 + k * 1024 + t * 4;
            const float4 f4 = *(const float4*)&outw[fidx];
            short4v s; s[0] = f2bf(f4.x); s[1] = f2bf(f4.y);
                       s[2] = f2bf(f4.z); s[3] = f2bf(f4.w);
            *(short4v*)&wb[fidx] = s;
        }
    }
}

// ---------------------------------------------------------------- cheb_attn
// grid (32, 8, 2) = (qt, h, b), block 512 (8 waves), 2 blocks/CU.
__global__ __launch_bounds__(512, 4) void cheb_attn(
    const float* __restrict__ qp, const float* __restrict__ kp,
    const unsigned char* __restrict__ msk,
    const float* __restrict__ ls, const float* __restrict__ cheb,
    const short* __restrict__ vt, short* __restrict__ flatb)
{
    __shared__ float s_kx[1024], s_ky[1024], s_kz[1024];   // kp SoA
    __shared__ __align__(8) unsigned char s_mask[1024];
    __shared__ float s_l1[4][32];
    __shared__ float s_pb[3][32 * 68];                      // groups 1..3 partial P

    const int t = threadIdx.x;
    const int qt = blockIdx.x, h = blockIdx.y, b = blockIdx.z;
    const int w = t >> 6, lane = t & 63;
    const int wg = w & 1, g = w >> 1;          // q band (16 rows), m group (256 m)
    const int arow = lane & 15, koct = lane >> 4;

    // stage kp (SoA) + mask
    #pragma unroll
    for (int mm_ = 0; mm_ < 2; ++mm_) {
        const int m = mm_ * 512 + t;
        const size_t base = ((size_t)b * 1024 + m) * 3;
        s_kx[m] = kp[base + 0];
        s_ky[m] = kp[base + 1];
        s_kz[m] = kp[base + 2];
    }
    *(unsigned short*)&s_mask[t * 2] =
        *(const unsigned short*)&msk[(size_t)b * 1024 + t * 2];

    const float lsv = ls[h];
    const float invls2 = 1.0f / (lsv * lsv);
    float cc[8]; float cs = 0.f;
    #pragma unroll
    for (int j = 0; j < 8; ++j) { cc[j] = cheb[h * 8 + j]; cs += cc[j]; }
    const float cm = cs * 0.125f;
    #pragma unroll
    for (int j = 0; j < 8; ++j) cc[j] -= cm;

    // this lane's q row (A-fragment row identity)
    const int qg = qt * 32 + wg * 16 + arow;
    const float qx = qp[((size_t)b * 1024 + qg) * 3 + 0];
    const float qy = qp[((size_t)b * 1024 + qg) * 3 + 1];
    const float qz = qp[((size_t)b * 1024 + qg) * 3 + 2];

    f32x4 acc[4] = {(f32x4)(0.f), (f32x4)(0.f), (f32x4)(0.f), (f32x4)(0.f)};
    const short* vtb = vt + ((size_t)(b * 8 + h) * 64) * 1024;
    float l1p = 0.f;

    __syncthreads();   // kp/mask staged — the ONLY pre-epilogue barrier

    #pragma unroll
    for (int tile = 0; tile < 4; ++tile) {
        const int m0 = g * 256 + tile * 64;
        short8v a[2];
        #pragma unroll
        for (int kk = 0; kk < 2; ++kk) {
            const int mb = m0 + kk * 32 + koct * 8;   // 8 consecutive m this lane owns
            f32x4 kx[2], ky[2], kz[2];
            kx[0] = *(const f32x4*)&s_kx[mb]; kx[1] = *(const f32x4*)&s_kx[mb + 4];
            ky[0] = *(const f32x4*)&s_ky[mb]; ky[1] = *(const f32x4*)&s_ky[mb + 4];
            kz[0] = *(const f32x4*)&s_kz[mb]; kz[1] = *(const f32x4*)&s_kz[mb + 4];
            const uint2 mmv = *(const uint2*)&s_mask[mb];
            const bool anymask = (mmv.x | mmv.y) != 0u;
            #pragma unroll
            for (int j = 0; j < 8; ++j) {
                const float dx = qx - kx[j >> 2][j & 3];
                const float dy = qy - ky[j >> 2][j & 3];
                const float dz = qz - kz[j >> 2][j & 3];
                const float x  = (dx * dx + dy * dy + dz * dz) * invls2;
                const float r  = (x - 1.f) * frcp(x + 1.f);
                const float r2 = r + r;
                float tp = 1.f, tc = r;
                float s  = cc[0] + cc[1] * r;
                #pragma unroll
                for (int c = 2; c < 8; ++c) {
                    const float tn = r2 * tc - tp;
                    s += cc[c] * tn; tp = tc; tc = tn;
                }
                if (anymask) {
                    const unsigned int mword = (j < 4) ? mmv.x : mmv.y;
                    if ((mword >> ((j & 3) * 8)) & 0xffu) s = 0.f;
                }
                l1p += fabsf(s);
                a[kk][j] = f2bf(s);
            }
        }
        // attend: B-frags straight from L2-resident Vt
        #pragma unroll
        for (int kk = 0; kk < 2; ++kk)
            #pragma unroll
            for (int f = 0; f < 4; ++f) {
                const short8v bf = *(const short8v*)
                    &vtb[(size_t)(f * 16 + arow) * 1024 + m0 + kk * 32 + koct * 8];
                acc[f] = __builtin_amdgcn_mfma_f32_16x16x32_bf16(a[kk], bf, acc[f], 0, 0, 0);
            }
    }

    // L1 partial: lanes {arow, arow+16, arow+32, arow+48} share q row
    l1p += __shfl_xor(l1p, 16);
    l1p += __shfl_xor(l1p, 32);
    if (koct == 0) s_l1[g][wg * 16 + arow] = l1p;

    if (g > 0) {
        #pragma unroll
        for (int f = 0; f < 4; ++f)
            #pragma unroll
            for (int j = 0; j < 4; ++j)
                s_pb[g - 1][(wg * 16 + koct * 4 + j) * 68 + f * 16 + arow] = acc[f][j];
    }
    __syncthreads();
    if (g == 0) {
        float rden[4];
        #pragma unroll
        for (int j = 0; j < 4; ++j) {
            const int row = wg * 16 + koct * 4 + j;
            rden[j] = frcp(s_l1[0][row] + s_l1[1][row] + s_l1[2][row]
                         + s_l1[3][row] + EPSF);
        }
        #pragma unroll
        for (int f = 0; f < 4; ++f)
            #pragma unroll
            for (int j = 0; j < 4; ++j) {
                const int row = wg * 16 + koct * 4 + j;
                const int col = f * 16 + arow;
                const float v = (acc[f][j]
                    + s_pb[0][row * 68 + col]
                    + s_pb[1][row * 68 + col]
                    + s_pb[2][row * 68 + col]) * rden[j];
                flatb[((size_t)b * 1024 + qt * 32 + row) * 512 + h * 64 + col]
                    = f2bf(v);
            }
    }
}

// ---------------------------------------------------------------- proj
// out[2048,512] = flat[2048,512] @ Wb[n,k]^T, bf16 MFMA, frags direct from
// L2-resident global. grid (32,16): 64 rows x 32 n per block; block 256.
__global__ __launch_bounds__(256) void proj(
    const short* __restrict__ flatb, const short* __restrict__ wb,
    float* __restrict__ out)
{
    const int t = threadIdx.x;
    const int r0 = blockIdx.x * 64, n0 = blockIdx.y * 32;
    const int w = t >> 6, lane = t & 63;
    const int arow = lane & 15, koct = lane >> 4;
    const int band = w * 16;

    f32x4 acc[2] = {(f32x4)(0.f), (f32x4)(0.f)};
    const short* ap = &flatb[(size_t)(r0 + band + arow) * 512];
    const short* b0 = &wb[(size_t)(n0 + arow) * 512];
    const short* b1 = &wb[(size_t)(n0 + 16 + arow) * 512];

    #pragma unroll 4
    for (int kk = 0; kk < 16; ++kk) {
        const int ko = kk * 32 + koct * 8;
        const short8v a   = *(const short8v*)&ap[ko];
        const short8v bf0 = *(const short8v*)&b0[ko];
        const short8v bf1 = *(const short8v*)&b1[ko];
        acc[0] = __builtin_amdgcn_mfma_f32_16x16x32_bf16(a, bf0, acc[0], 0, 0, 0);
        acc[1] = __builtin_amdgcn_mfma_f32_16x16x32_bf16(a, bf1, acc[1], 0, 0, 0);
    }
    #pragma unroll
    for (int f = 0; f < 2; ++f)
        #pragma unroll
        for (int j = 0; j < 4; ++j)
            out[((size_t)(r0 + band + koct * 4 + j)) * 512 + n0 + f * 16 + arow]
                = acc[f][j];
}

extern "C" void kernel_launch(void* const* d_in, const int* in_sizes, int n_in,
                              void* d_out, int out_size, void* d_ws, size_t ws_size,
                              hipStream_t stream) {
    const float* qp   = (const float*)d_in[0];
    const float* kp   = (const float*)d_in[1];
    const float* vals = (const float*)d_in[2];
    const unsigned char* msk = (const unsigned char*)d_in[3];
    const float* ls   = (const float*)d_in[4];
    const float* cheb = (const float*)d_in[5];
    const float* outw = (const float*)d_in[6];
    float* out = (float*)d_out;

    short* vtp   = (short*)d_ws;
    short* wbp   = vtp + WB_OFF_S;
    short* flatb = vtp + FLAT_OFF_S;

    prep<<<288, 256, 0, stream>>>(vals, outw, vtp, wbp);
    cheb_attn<<<dim3(32, 8, 2), 512, 0, stream>>>(qp, kp, msk, ls, cheb, vtp, flatb);
    proj<<<dim3(32, 16), 256, 0, stream>>>(flatb, wbp, out);
}

// Round 3
// 40.811 us; speedup vs baseline: 1.6221x; 1.0134x over previous
//
#include <hip/hip_runtime.h>
#include <hip/hip_bf16.h>

// LearnableChebyshevKernelAttention, MI355X — MFMA, barrier-free main loop,
// loads-first software pipeline. Score numerics are BIT-IDENTICAL to the
// verified round-1 kernel (Chebyshev recurrence; monomial rewrite failed
// accuracy: systematic cancellation error in the asymptotic-zero regime).
// B=2, Q=M=1024, DIM=3, H=8, V=64, OUT=512, C=8.
//
// prep:      values [b,m,h,v] f32 -> Vt [b,h,v,m] bf16, out_w f32 -> bf16.
// cheb_attn: grid (32,8,2) = (qt of 32 q, h, b), block 512 (8 waves).
//            Scores computed DIRECTLY in the MFMA A-fragment register layout
//            (lane arow owns q; koct owns an 8-m octet) -> no score LDS, no
//            per-tile barriers. Per tile: issue Vt B-frag global loads + LDS
//            k-reads FIRST, then ~900 cyc of score VALU hides the latency,
//            then 8 MFMAs.
// proj:      flat bf16 [2048,512] @ Wb[n,k]^T via MFMA, frags straight from
//            L2-resident global, no LDS, no barriers. grid (32,16), block 256.

typedef __attribute__((ext_vector_type(8))) short short8v;
typedef __attribute__((ext_vector_type(4))) short short4v;
typedef __attribute__((ext_vector_type(4))) float f32x4;

#define EPSF 1e-5f

__device__ __forceinline__ float frcp(float x) { return __builtin_amdgcn_rcpf(x); }
__device__ __forceinline__ short f2bf(float f) {
    __hip_bfloat16 h = __float2bfloat16(f);   // RNE
    return *reinterpret_cast<short*>(&h);
}

// ws layout (shorts): Vt bf16 [2*8*64*1024] | Wb bf16 [512*512] | flat bf16 [2*1024*512]
#define VT_ELEMS   (2u * 8u * 64u * 1024u)
#define WB_OFF_S   (VT_ELEMS)
#define FLAT_OFF_S (VT_ELEMS + 512u * 512u)

// ---------------------------------------------------------------- prep
// grid 288: blocks 0..255 transpose one (b,h,64m) values tile; 256..287 convert W.
__global__ __launch_bounds__(256) void prep(
    const float* __restrict__ vals, const float* __restrict__ outw,
    short* __restrict__ vt, short* __restrict__ wb)
{
    const int bid = blockIdx.x, t = threadIdx.x;
    if (bid < 256) {
        __shared__ float sf[64 * 68];
        const int b = bid >> 7, h = (bid >> 4) & 7, m0 = (bid & 15) * 64;
        #pragma unroll
        for (int fi = 0; fi < 4; ++fi) {
            const int idx = fi * 256 + t, mr = idx >> 4, c4 = idx & 15;
            const float4 v4 = *(const float4*)&vals[
                (((size_t)b * 1024 + m0 + mr) * 8 + h) * 64 + c4 * 4];
            *(float4*)&sf[mr * 68 + c4 * 4] = v4;
        }
        __syncthreads();
        const int v = t >> 2, mo = t & 3;
        short8v o0, o1;
        #pragma unroll
        for (int i = 0; i < 8; ++i) o0[i] = f2bf(sf[(mo * 16 + i) * 68 + v]);
        #pragma unroll
        for (int i = 0; i < 8; ++i) o1[i] = f2bf(sf[(mo * 16 + 8 + i) * 68 + v]);
        const size_t ob = ((size_t)(b * 8 + h) * 64 + v) * 1024 + m0 + mo * 16;
        *(short8v*)&vt[ob] = o0;
        *(short8v*)&vt[ob + 8] = o1;
    } else {
        const int wi = bid - 256;            // 0..31, 8192 floats each
        #pragma unroll
        for (int k = 0; k < 8; ++k) {
            const int fidx = wi * 8192 + k * 1024 + t * 4;
            const float4 f4 = *(const float4*)&outw[fidx];
            short4v s; s[0] = f2bf(f4.x); s[1] = f2bf(f4.y);
                       s[2] = f2bf(f4.z); s[3] = f2bf(f4.w);
            *(short4v*)&wb[fidx] = s;
        }
    }
}

// ---------------------------------------------------------------- cheb_attn
// grid (32, 8, 2) = (qt, h, b), block 512 (8 waves), 2 blocks/CU.
__global__ __launch_bounds__(512, 4) void cheb_attn(
    const float* __restrict__ qp, const float* __restrict__ kp,
    const unsigned char* __restrict__ msk,
    const float* __restrict__ ls, const float* __restrict__ cheb,
    const short* __restrict__ vt, short* __restrict__ flatb)
{
    __shared__ float s_kx[1024], s_ky[1024], s_kz[1024];   // kp SoA
    __shared__ __align__(8) unsigned char s_mask[1024];
    __shared__ float s_l1[4][32];
    __shared__ float s_pb[3][32 * 68];                      // groups 1..3 partial P

    const int t = threadIdx.x;
    const int qt = blockIdx.x, h = blockIdx.y, b = blockIdx.z;
    const int w = t >> 6, lane = t & 63;
    const int wg = w & 1, g = w >> 1;          // q band (16 rows), m group (256 m)
    const int arow = lane & 15, koct = lane >> 4;

    // stage kp (SoA) + mask
    #pragma unroll
    for (int mm_ = 0; mm_ < 2; ++mm_) {
        const int m = mm_ * 512 + t;
        const size_t base = ((size_t)b * 1024 + m) * 3;
        s_kx[m] = kp[base + 0];
        s_ky[m] = kp[base + 1];
        s_kz[m] = kp[base + 2];
    }
    *(unsigned short*)&s_mask[t * 2] =
        *(const unsigned short*)&msk[(size_t)b * 1024 + t * 2];

    // per-head constants (wave-uniform -> scalar regs). Verified numerics.
    const float lsv = ls[h];
    const float invls2 = 1.0f / (lsv * lsv);
    float cc[8]; float cs = 0.f;
    #pragma unroll
    for (int j = 0; j < 8; ++j) { cc[j] = cheb[h * 8 + j]; cs += cc[j]; }
    const float cm = cs * 0.125f;
    #pragma unroll
    for (int j = 0; j < 8; ++j) cc[j] -= cm;

    // this lane's q row (A-fragment row identity)
    const int qg = qt * 32 + wg * 16 + arow;
    const float qx = qp[((size_t)b * 1024 + qg) * 3 + 0];
    const float qy = qp[((size_t)b * 1024 + qg) * 3 + 1];
    const float qz = qp[((size_t)b * 1024 + qg) * 3 + 2];

    f32x4 acc[4] = {(f32x4)(0.f), (f32x4)(0.f), (f32x4)(0.f), (f32x4)(0.f)};
    const short* vtb = vt + ((size_t)(b * 8 + h) * 64) * 1024;
    float l1p = 0.f;

    __syncthreads();   // kp/mask staged — the ONLY pre-epilogue barrier

    #pragma unroll
    for (int tile = 0; tile < 4; ++tile) {
        const int m0 = g * 256 + tile * 64;

        // ---- 1) issue Vt B-frag loads (L2) — consumed only at step 3
        short8v bfr[2][4];
        #pragma unroll
        for (int kk = 0; kk < 2; ++kk)
            #pragma unroll
            for (int f = 0; f < 4; ++f)
                bfr[kk][f] = *(const short8v*)
                    &vtb[(size_t)(f * 16 + arow) * 1024 + m0 + kk * 32 + koct * 8];

        // ---- 1b) issue LDS k reads + mask for both kk groups
        f32x4 kx[2][2], ky[2][2], kz[2][2];
        uint2 mmv[2];
        #pragma unroll
        for (int kk = 0; kk < 2; ++kk) {
            const int mb = m0 + kk * 32 + koct * 8;
            kx[kk][0] = *(const f32x4*)&s_kx[mb]; kx[kk][1] = *(const f32x4*)&s_kx[mb + 4];
            ky[kk][0] = *(const f32x4*)&s_ky[mb]; ky[kk][1] = *(const f32x4*)&s_ky[mb + 4];
            kz[kk][0] = *(const f32x4*)&s_kz[mb]; kz[kk][1] = *(const f32x4*)&s_kz[mb + 4];
            mmv[kk] = *(const uint2*)&s_mask[mb];
        }

        // ---- 2) 16 scores, verified Chebyshev-recurrence numerics,
        //         in A-frag layout
        short8v a[2];
        #pragma unroll
        for (int kk = 0; kk < 2; ++kk) {
            const bool anymask = (mmv[kk].x | mmv[kk].y) != 0u;
            #pragma unroll
            for (int j = 0; j < 8; ++j) {
                const float dx = qx - kx[kk][j >> 2][j & 3];
                const float dy = qy - ky[kk][j >> 2][j & 3];
                const float dz = qz - kz[kk][j >> 2][j & 3];
                const float x  = (dx * dx + dy * dy + dz * dz) * invls2;
                const float r  = (x - 1.f) * frcp(x + 1.f);
                const float r2 = r + r;
                float tp = 1.f, tc = r;
                float s  = cc[0] + cc[1] * r;
                #pragma unroll
                for (int c = 2; c < 8; ++c) {
                    const float tn = r2 * tc - tp;
                    s += cc[c] * tn; tp = tc; tc = tn;
                }
                if (anymask) {
                    const unsigned int mword = (j < 4) ? mmv[kk].x : mmv[kk].y;
                    if ((mword >> ((j & 3) * 8)) & 0xffu) s = 0.f;
                }
                l1p += fabsf(s);
                a[kk][j] = f2bf(s);
            }
        }

        // ---- 3) attend
        #pragma unroll
        for (int kk = 0; kk < 2; ++kk)
            #pragma unroll
            for (int f = 0; f < 4; ++f)
                acc[f] = __builtin_amdgcn_mfma_f32_16x16x32_bf16(
                    a[kk], bfr[kk][f], acc[f], 0, 0, 0);
    }

    // L1 partial: lanes {arow, arow+16, arow+32, arow+48} share q row
    l1p += __shfl_xor(l1p, 16);
    l1p += __shfl_xor(l1p, 32);
    if (koct == 0) s_l1[g][wg * 16 + arow] = l1p;

    if (g > 0) {
        #pragma unroll
        for (int f = 0; f < 4; ++f)
            #pragma unroll
            for (int j = 0; j < 4; ++j)
                s_pb[g - 1][(wg * 16 + koct * 4 + j) * 68 + f * 16 + arow] = acc[f][j];
    }
    __syncthreads();
    if (g == 0) {
        float rden[4];
        #pragma unroll
        for (int j = 0; j < 4; ++j) {
            const int row = wg * 16 + koct * 4 + j;
            rden[j] = frcp(s_l1[0][row] + s_l1[1][row] + s_l1[2][row]
                         + s_l1[3][row] + EPSF);
        }
        #pragma unroll
        for (int f = 0; f < 4; ++f)
            #pragma unroll
            for (int j = 0; j < 4; ++j) {
                const int row = wg * 16 + koct * 4 + j;
                const int col = f * 16 + arow;
                const float v = (acc[f][j]
                    + s_pb[0][row * 68 + col]
                    + s_pb[1][row * 68 + col]
                    + s_pb[2][row * 68 + col]) * rden[j];
                flatb[((size_t)b * 1024 + qt * 32 + row) * 512 + h * 64 + col]
                    = f2bf(v);
            }
    }
}

// ---------------------------------------------------------------- proj
// out[2048,512] = flat[2048,512] @ Wb[n,k]^T, bf16 MFMA, frags direct from
// L2-resident global. grid (32,16): 64 rows x 32 n per block; block 256.
__global__ __launch_bounds__(256, 4) void proj(
    const short* __restrict__ flatb, const short* __restrict__ wb,
    float* __restrict__ out)
{
    const int t = threadIdx.x;
    const int r0 = blockIdx.x * 64, n0 = blockIdx.y * 32;
    const int w = t >> 6, lane = t & 63;
    const int arow = lane & 15, koct = lane >> 4;
    const int band = w * 16;

    f32x4 acc[2] = {(f32x4)(0.f), (f32x4)(0.f)};
    const short* ap = &flatb[(size_t)(r0 + band + arow) * 512];
    const short* b0 = &wb[(size_t)(n0 + arow) * 512];
    const short* b1 = &wb[(size_t)(n0 + 16 + arow) * 512];

    #pragma unroll 8
    for (int kk = 0; kk < 16; ++kk) {
        const int ko = kk * 32 + koct * 8;
        const short8v a   = *(const short8v*)&ap[ko];
        const short8v bf0 = *(const short8v*)&b0[ko];
        const short8v bf1 = *(const short8v*)&b1[ko];
        acc[0] = __builtin_amdgcn_mfma_f32_16x16x32_bf16(a, bf0, acc[0], 0, 0, 0);
        acc[1] = __builtin_amdgcn_mfma_f32_16x16x32_bf16(a, bf1, acc[1], 0, 0, 0);
    }
    #pragma unroll
    for (int f = 0; f < 2; ++f)
        #pragma unroll
        for (int j = 0; j < 4; ++j)
            out[((size_t)(r0 + band + koct * 4 + j)) * 512 + n0 + f * 16 + arow]
                = acc[f][j];
}

extern "C" void kernel_launch(void* const* d_in, const int* in_sizes, int n_in,
                              void* d_out, int out_size, void* d_ws, size_t ws_size,
                              hipStream_t stream) {
    const float* qp   = (const float*)d_in[0];
    const float* kp   = (const float*)d_in[1];
    const float* vals = (const float*)d_in[2];
    const unsigned char* msk = (const unsigned char*)d_in[3];
    const float* ls   = (const float*)d_in[4];
    const float* cheb = (const float*)d_in[5];
    const float* outw = (const float*)d_in[6];
    float* out = (float*)d_out;

    short* vtp   = (short*)d_ws;
    short* wbp   = vtp + WB_OFF_S;
    short* flatb = vtp + FLAT_OFF_S;

    prep<<<288, 256, 0, stream>>>(vals, outw, vtp, wbp);
    cheb_attn<<<dim3(32, 8, 2), 512, 0, stream>>>(qp, kp, msk, ls, cheb, vtp, flatb);
    proj<<<dim3(32, 16), 256, 0, stream>>>(flatb, wbp, out);
}